// Round 2
// baseline (629.979 us; speedup 1.0000x reference)
//
#include <hip/hip_runtime.h>
#include <hip/hip_bf16.h>

typedef __attribute__((ext_vector_type(8))) short bf16x8;
typedef __attribute__((ext_vector_type(4))) float f32x4;

#define MFMA16(a, b, c) __builtin_amdgcn_mfma_f32_16x16x32_bf16((a), (b), (c), 0, 0, 0)

#define N_ 64
#define C_ 192
#define T_ 128
#define V_ 25
#define S_ 3
#define MID 64
#define TV 3200          // T_*V_
#define C3 576           // 3*C_
#define OUT_ELEMS 39321600ULL

static __device__ __forceinline__ float bf2f(ushort u) {
    union { unsigned int i; float f; } x; x.i = ((unsigned int)u) << 16; return x.f;
}
static __device__ __forceinline__ ushort f2bf(float f) {
    union { float f; unsigned int i; } x; x.f = f;
    unsigned int r = x.i + 0x7fffu + ((x.i >> 16) & 1u);
    return (ushort)(r >> 16);
}

// ---------------------------------------------------------------------------
// T1: x[n][c][m] (fp32) -> xT[n][m][c] (bf16)   per-n 192x3200 transpose+cvt
// ---------------------------------------------------------------------------
__global__ __launch_bounds__(256) void t1_transpose(const float* __restrict__ x,
                                                    ushort* __restrict__ xT) {
    int mt = blockIdx.x, ct = blockIdx.y, n = blockIdx.z;
    int m0 = mt * 64, c0 = ct * 64;
    __shared__ ushort tile[64 * 72];
    int tid = threadIdx.x;
    const float* xb = x + ((size_t)n * C_ + c0) * TV + m0;
#pragma unroll
    for (int j = 0; j < 4; j++) {
        int chunk = tid + j * 256;          // 1024 chunks of 4 floats
        int r = chunk >> 4, c4 = chunk & 15;
        float4 d = *(const float4*)(xb + (size_t)r * TV + c4 * 4);
        ushort* dst = &tile[r * 72 + c4 * 4];
        dst[0] = f2bf(d.x); dst[1] = f2bf(d.y); dst[2] = f2bf(d.z); dst[3] = f2bf(d.w);
    }
    __syncthreads();
    ushort* ob = xT + ((size_t)n * TV + m0) * C_ + c0;
    int cc = tid & 63;
#pragma unroll
    for (int j = 0; j < 16; j++) {
        int mm = (tid >> 6) + j * 4;
        ob[(size_t)mm * C_ + cc] = tile[cc * 72 + mm];
    }
}

// ---------------------------------------------------------------------------
// K1: qkvT[n][m][o] = sum_k xT[n][m][k] * Wqkv[o][k] + bqkv[o]   (bf16 out)
// tile 128(m) x 64(o), full K=192 staged once. 16x16x32 bf16 MFMA.
// ---------------------------------------------------------------------------
__global__ __launch_bounds__(256) void k1_qkv(const ushort* __restrict__ xT,
                                              const float* __restrict__ W,
                                              const float* __restrict__ bias,
                                              ushort* __restrict__ qkvT) {
    int m0 = blockIdx.x * 128, o0 = blockIdx.y * 64, n = blockIdx.z;
    __shared__ ushort As[128 * 200];   // rows m, 192 + 8 pad
    __shared__ ushort Bs[64 * 200];    // rows o
    __shared__ float biasS[64];
    int tid = threadIdx.x;

    const ushort* ab = xT + ((size_t)n * TV + m0) * C_;
#pragma unroll
    for (int j = 0; j < 12; j++) {
        int chunk = tid + j * 256;          // 3072 = 128 rows * 24 chunks
        int r = chunk / 24, c16 = chunk % 24;
        uint4 d = *(const uint4*)(ab + (size_t)r * C_ + c16 * 8);
        *(uint4*)&As[r * 200 + c16 * 8] = d;
    }
#pragma unroll
    for (int j = 0; j < 12; j++) {
        int chunk = tid + j * 256;          // 3072 = 64 rows * 48 float4 chunks
        int r = chunk / 48, c4 = chunk % 48;
        float4 d = *(const float4*)(W + (size_t)(o0 + r) * C_ + c4 * 4);
        ushort* dst = &Bs[r * 200 + c4 * 4];
        dst[0] = f2bf(d.x); dst[1] = f2bf(d.y); dst[2] = f2bf(d.z); dst[3] = f2bf(d.w);
    }
    if (tid < 64) biasS[tid] = bias[o0 + tid];
    __syncthreads();

    int wave = tid >> 6, lane = tid & 63;
    int mb = (wave >> 1) * 64, ob = (wave & 1) * 32;
    int lrow = lane & 15, lk = lane >> 4;

    f32x4 acc[4][2];
#pragma unroll
    for (int i = 0; i < 4; i++)
#pragma unroll
        for (int j = 0; j < 2; j++) acc[i][j] = (f32x4){0.f, 0.f, 0.f, 0.f};

#pragma unroll
    for (int ks = 0; ks < 6; ks++) {
        bf16x8 a[4], b[2];
#pragma unroll
        for (int mt = 0; mt < 4; mt++)
            a[mt] = *(const bf16x8*)&As[(mb + mt * 16 + lrow) * 200 + ks * 32 + lk * 8];
#pragma unroll
        for (int ot = 0; ot < 2; ot++)
            b[ot] = *(const bf16x8*)&Bs[(ob + ot * 16 + lrow) * 200 + ks * 32 + lk * 8];
#pragma unroll
        for (int mt = 0; mt < 4; mt++)
#pragma unroll
            for (int ot = 0; ot < 2; ot++)
                acc[mt][ot] = MFMA16(a[mt], b[ot], acc[mt][ot]);
    }

    ushort* op = qkvT + ((size_t)n * TV + m0) * C3 + o0;
#pragma unroll
    for (int mt = 0; mt < 4; mt++) {
#pragma unroll
        for (int ot = 0; ot < 2; ot++) {
            int o = ob + ot * 16 + lrow;
            float bv = biasS[o];
#pragma unroll
            for (int r = 0; r < 4; r++) {
                int m = mb + mt * 16 + lk * 4 + r;
                op[(size_t)m * C3 + o] = f2bf(acc[mt][ot][r] + bv);
            }
        }
    }
}

// ---------------------------------------------------------------------------
// K2: att[n][s][u][v] = tanh( sum_{t,c} q[u] k[v] / 8192 )  (fp32 out)
// one block per (s, n); each wave independently handles t = w mod 4 (no
// barriers in the K-loop), cross-wave reduce at the end.
// ---------------------------------------------------------------------------
__global__ __launch_bounds__(256) void k2_att(const ushort* __restrict__ qkvT,
                                              float* __restrict__ attOut) {
    int s = blockIdx.x, n = blockIdx.y;
    __shared__ ushort tiles[4 * 2 * 32 * 72];   // [wave][q/k][32 rows][64+8]
    __shared__ float red[4 * 32 * 33];
    int tid = threadIdx.x, wave = tid >> 6, lane = tid & 63;
    ushort* myQ = &tiles[wave * 2 * 2304];
    ushort* myK = myQ + 2304;

    // zero pad rows 25..31 of both tiles (never written again)
    if (lane < 63) {
        *(uint4*)&myQ[1800 + lane * 8] = (uint4){0, 0, 0, 0};
        *(uint4*)&myK[1800 + lane * 8] = (uint4){0, 0, 0, 0};
    }

    const size_t nbase = (size_t)n * TV * C3;
    int qoff = s * MID;
    int koff = C_ + s * MID;
    int lrow = lane & 15, lk = lane >> 4;

    f32x4 acc[2][2];
#pragma unroll
    for (int i = 0; i < 2; i++)
#pragma unroll
        for (int j = 0; j < 2; j++) acc[i][j] = (f32x4){0.f, 0.f, 0.f, 0.f};

    uint4 pre[7];
#pragma unroll
    for (int j = 0; j < 7; j++) {
        int idx = lane + j * 64;
        if (idx < 400) {
            int op = idx / 200, rr = idx % 200;
            int row = rr >> 3, c16 = rr & 7;
            int chan = (op ? koff : qoff) + c16 * 8;
            pre[j] = *(const uint4*)(qkvT + nbase + (size_t)(wave * V_ + row) * C3 + chan);
        }
    }

    int t = wave;
    for (int i = 0; i < 32; i++) {
#pragma unroll
        for (int j = 0; j < 7; j++) {
            int idx = lane + j * 64;
            if (idx < 400) {
                int op = idx / 200, rr = idx % 200;
                int row = rr >> 3, c16 = rr & 7;
                *(uint4*)((op ? myK : myQ) + row * 72 + c16 * 8) = pre[j];
            }
        }
        uint4 nxt[7];
        if (i < 31) {
            int tn = t + 4;
#pragma unroll
            for (int j = 0; j < 7; j++) {
                int idx = lane + j * 64;
                if (idx < 400) {
                    int op = idx / 200, rr = idx % 200;
                    int row = rr >> 3, c16 = rr & 7;
                    int chan = (op ? koff : qoff) + c16 * 8;
                    nxt[j] = *(const uint4*)(qkvT + nbase + (size_t)(tn * V_ + row) * C3 + chan);
                }
            }
        }
#pragma unroll
        for (int ks = 0; ks < 2; ks++) {
            bf16x8 a0 = *(const bf16x8*)&myQ[lrow * 72 + ks * 32 + lk * 8];
            bf16x8 a1 = *(const bf16x8*)&myQ[(16 + lrow) * 72 + ks * 32 + lk * 8];
            bf16x8 b0 = *(const bf16x8*)&myK[lrow * 72 + ks * 32 + lk * 8];
            bf16x8 b1 = *(const bf16x8*)&myK[(16 + lrow) * 72 + ks * 32 + lk * 8];
            acc[0][0] = MFMA16(a0, b0, acc[0][0]);
            acc[0][1] = MFMA16(a0, b1, acc[0][1]);
            acc[1][0] = MFMA16(a1, b0, acc[1][0]);
            acc[1][1] = MFMA16(a1, b1, acc[1][1]);
        }
#pragma unroll
        for (int j = 0; j < 7; j++) pre[j] = nxt[j];
        t += 4;
    }

#pragma unroll
    for (int ub = 0; ub < 2; ub++)
#pragma unroll
        for (int vb = 0; vb < 2; vb++)
#pragma unroll
            for (int r = 0; r < 4; r++) {
                int u = ub * 16 + lk * 4 + r, v = vb * 16 + lrow;
                red[wave * 1056 + u * 33 + v] = acc[ub][vb][r];
            }
    __syncthreads();

    const size_t attbase = ((size_t)n * S_ + s) * V_ * V_;
    for (int idx = tid; idx < 1024; idx += 256) {
        int u = idx >> 5, v = idx & 31;
        if (u < V_ && v < V_) {
            float sum = red[u * 33 + v] + red[1056 + u * 33 + v] +
                        red[2112 + u * 33 + v] + red[3168 + u * 33 + v];
            attOut[attbase + u * V_ + v] = tanhf(sum * (1.0f / 8192.0f));
        }
    }
}

// ---------------------------------------------------------------------------
// K3: yT[n][t*25+u][c'] = sum_v att[n][s(c')][u][v] * qkv_v[n][t*25+v][c']
// one block per (t, n), 192 threads (thread = c'; wave = subset s).
// att is read from the fp32 output segment written by K2 (same stream).
// ---------------------------------------------------------------------------
__global__ __launch_bounds__(192) void k3_y(const ushort* __restrict__ qkvT,
                                            const float* __restrict__ attF,
                                            ushort* __restrict__ yT) {
    int t = blockIdx.x, n = blockIdx.y;
    __shared__ float attS[3 * 700];   // [s][u][28 pad]
    int tid = threadIdx.x;
    const float* ab = attF + (size_t)n * (S_ * V_ * V_);
    for (int idx = tid; idx < S_ * V_ * V_; idx += 192) {
        int s = idx / 625, r = idx % 625;
        attS[s * 700 + (r / 25) * 28 + (r % 25)] = ab[idx];
    }
    __syncthreads();

    int c = tid;
    int s = c >> 6;
    const ushort* vb = qkvT + ((size_t)n * TV + (size_t)t * V_) * C3 + 2 * C_ + c;
    float vreg[25];
#pragma unroll
    for (int v = 0; v < 25; v++) vreg[v] = bf2f(vb[(size_t)v * C3]);

    ushort* yb = yT + ((size_t)n * TV + (size_t)t * V_) * C_ + c;
    const float* as = &attS[s * 700];
    for (int u = 0; u < 25; u++) {
        float a = 0.f;
#pragma unroll
        for (int v = 0; v < 25; v++) a += as[u * 28 + v] * vreg[v];
        yb[(size_t)u * C_] = f2bf(a);
    }
}

// ---------------------------------------------------------------------------
// K4: out[n][o][m] = LeakyReLU(x + (yT.Wff^T)*inv[o] + shift[o], 0.1)  fp32
// same GEMM structure as K1; epilogue transposes through LDS (fp32) for
// coalesced float4 stores in the (N,C,T,V) output layout.
// ---------------------------------------------------------------------------
__global__ __launch_bounds__(256) void k4_out(const ushort* __restrict__ yT,
                                              const float* __restrict__ Wff,
                                              const float* __restrict__ bff,
                                              const float* __restrict__ gamma,
                                              const float* __restrict__ beta,
                                              const float* __restrict__ rmean,
                                              const float* __restrict__ rvar,
                                              const float* __restrict__ x,
                                              float* __restrict__ out) {
    int m0 = blockIdx.x * 128, o0 = blockIdx.y * 64, n = blockIdx.z;
    __shared__ ushort As[128 * 200];   // 51200 B; reused as fp32 zT (64x132)
    __shared__ ushort Bs[64 * 200];
    __shared__ float invS[64], shiftS[64];
    int tid = threadIdx.x;

    const ushort* ab = yT + ((size_t)n * TV + m0) * C_;
#pragma unroll
    for (int j = 0; j < 12; j++) {
        int chunk = tid + j * 256;
        int r = chunk / 24, c16 = chunk % 24;
        uint4 d = *(const uint4*)(ab + (size_t)r * C_ + c16 * 8);
        *(uint4*)&As[r * 200 + c16 * 8] = d;
    }
#pragma unroll
    for (int j = 0; j < 12; j++) {
        int chunk = tid + j * 256;          // 3072 = 64 rows * 48 float4 chunks
        int r = chunk / 48, c4 = chunk % 48;
        float4 d = *(const float4*)(Wff + (size_t)(o0 + r) * C_ + c4 * 4);
        ushort* dst = &Bs[r * 200 + c4 * 4];
        dst[0] = f2bf(d.x); dst[1] = f2bf(d.y); dst[2] = f2bf(d.z); dst[3] = f2bf(d.w);
    }
    if (tid < 64) {
        int o = o0 + tid;
        float inv = gamma[o] * rsqrtf(rvar[o] + 1e-5f);
        invS[tid] = inv;
        shiftS[tid] = beta[o] - rmean[o] * inv + bff[o] * inv;
    }
    __syncthreads();

    int wave = tid >> 6, lane = tid & 63;
    int mb = (wave >> 1) * 64, ob = (wave & 1) * 32;
    int lrow = lane & 15, lk = lane >> 4;

    f32x4 acc[4][2];
#pragma unroll
    for (int i = 0; i < 4; i++)
#pragma unroll
        for (int j = 0; j < 2; j++) acc[i][j] = (f32x4){0.f, 0.f, 0.f, 0.f};

#pragma unroll
    for (int ks = 0; ks < 6; ks++) {
        bf16x8 a[4], b[2];
#pragma unroll
        for (int mt = 0; mt < 4; mt++)
            a[mt] = *(const bf16x8*)&As[(mb + mt * 16 + lrow) * 200 + ks * 32 + lk * 8];
#pragma unroll
        for (int ot = 0; ot < 2; ot++)
            b[ot] = *(const bf16x8*)&Bs[(ob + ot * 16 + lrow) * 200 + ks * 32 + lk * 8];
#pragma unroll
        for (int mt = 0; mt < 4; mt++)
#pragma unroll
            for (int ot = 0; ot < 2; ot++)
                acc[mt][ot] = MFMA16(a[mt], b[ot], acc[mt][ot]);
    }

    __syncthreads();          // done reading As; reuse as fp32 zT[o][m] stride 132
    float* zT = (float*)As;
#pragma unroll
    for (int mt = 0; mt < 4; mt++)
#pragma unroll
        for (int ot = 0; ot < 2; ot++) {
            int o = ob + ot * 16 + lrow;
            float inv = invS[o], sh = shiftS[o];
#pragma unroll
            for (int r = 0; r < 4; r++) {
                int m = mb + mt * 16 + lk * 4 + r;
                zT[o * 132 + m] = acc[mt][ot][r] * inv + sh;
            }
        }
    __syncthreads();

    const float* xb = x + ((size_t)n * C_ + o0) * TV + m0;
    float* ob2 = out + ((size_t)n * C_ + o0) * TV + m0;
#pragma unroll
    for (int j = 0; j < 8; j++) {
        int chunk = tid + j * 256;          // 2048 = 64 rows x 32 float4 chunks
        int o = chunk >> 5, m4 = chunk & 31;
        float4 zv = *(float4*)&zT[o * 132 + m4 * 4];
        float4 xv = *(const float4*)(xb + (size_t)o * TV + m4 * 4);
        float4 res;
        float a;
        a = xv.x + zv.x; res.x = (a >= 0.f) ? a : 0.1f * a;
        a = xv.y + zv.y; res.y = (a >= 0.f) ? a : 0.1f * a;
        a = xv.z + zv.z; res.z = (a >= 0.f) ? a : 0.1f * a;
        a = xv.w + zv.w; res.w = (a >= 0.f) ? a : 0.1f * a;
        *(float4*)(ob2 + (size_t)o * TV + m4 * 4) = res;
    }
}

// ---------------------------------------------------------------------------
extern "C" void kernel_launch(void* const* d_in, const int* in_sizes, int n_in,
                              void* d_out, int out_size, void* d_ws, size_t ws_size,
                              hipStream_t stream) {
    (void)in_sizes; (void)n_in; (void)out_size; (void)ws_size;
    const float* x    = (const float*)d_in[0];
    const float* Wqkv = (const float*)d_in[1];
    const float* bqkv = (const float*)d_in[2];
    const float* Wff  = (const float*)d_in[3];
    const float* bff  = (const float*)d_in[4];
    const float* gam  = (const float*)d_in[5];
    const float* bet  = (const float*)d_in[6];
    const float* rme  = (const float*)d_in[7];
    const float* rva  = (const float*)d_in[8];
    float* out = (float*)d_out;
    float* attOut = out + OUT_ELEMS;   // fp32 att segment of the output tuple

    char* ws = (char*)d_ws;
    ushort* xT   = (ushort*)ws;                                   // 78,643,200 B
    ushort* qkvT = (ushort*)(ws + 78643200);                      // 235,929,600 B
    ushort* yT   = xT;                                            // reuse (xT dead after K1)

    t1_transpose<<<dim3(50, 3, 64), 256, 0, stream>>>(x, xT);
    k1_qkv<<<dim3(25, 9, 64), 256, 0, stream>>>(xT, Wqkv, bqkv, qkvT);
    k2_att<<<dim3(3, 64), 256, 0, stream>>>(qkvT, attOut);
    k3_y<<<dim3(128, 64), 192, 0, stream>>>(qkvT, attOut, yT);
    k4_out<<<dim3(25, 3, 64), 256, 0, stream>>>(yT, Wff, bff, gam, bet, rme, rva, x, out);
}

// Round 3
// 526.750 us; speedup vs baseline: 1.1960x; 1.1960x over previous
//
#include <hip/hip_runtime.h>
#include <hip/hip_bf16.h>

typedef __attribute__((ext_vector_type(8))) short bf16x8;
typedef __attribute__((ext_vector_type(4))) float f32x4;

#define MFMA16(a, b, c) __builtin_amdgcn_mfma_f32_16x16x32_bf16((a), (b), (c), 0, 0, 0)

#define N_ 64
#define C_ 192
#define T_ 128
#define V_ 25
#define S_ 3
#define MID 64
#define TV 3200          // T_*V_
#define C3 576           // 3*C_
#define OUT_ELEMS 39321600ULL
#define NCHUNK 16        // T-chunks for k2 partials
#define PSTRIDE 640      // padded 25*25 partial stride (floats)

static __device__ __forceinline__ float bf2f(ushort u) {
    union { unsigned int i; float f; } x; x.i = ((unsigned int)u) << 16; return x.f;
}
static __device__ __forceinline__ ushort f2bf(float f) {
    union { float f; unsigned int i; } x; x.f = f;
    unsigned int r = x.i + 0x7fffu + ((x.i >> 16) & 1u);
    return (ushort)(r >> 16);
}

// ---------------------------------------------------------------------------
// K1: qkvT[n][m][o] = sum_k x[n][k][m] * Wqkv[o][k] + bqkv[o]   (bf16 out)
// Fuses the x transpose (fp32 [c][m] -> bf16 As[m][c]) into staging.
// A-panel staged ONCE per block; loop over all 9 o-tiles (W is L2-resident).
// ---------------------------------------------------------------------------
__global__ __launch_bounds__(256) void k1_qkv(const float* __restrict__ x,
                                              const float* __restrict__ W,
                                              const float* __restrict__ bias,
                                              ushort* __restrict__ qkvT) {
    int m0 = blockIdx.x * 128, n = blockIdx.y;
    __shared__ ushort As[128 * 200];   // [m][c], c stride 200
    __shared__ ushort Bs[64 * 200];    // [o][c]; front 17.9KB aliased as scratch
    __shared__ float biasS[64];
    ushort* scratch = Bs;              // 64 x 140 (c-major, m-contig)
    int tid = threadIdx.x;

    // ---- stage A: 3 groups of 64 channels ----
    for (int cg = 0; cg < 3; cg++) {
        __syncthreads();
#pragma unroll
        for (int j = 0; j < 8; j++) {
            int chunk = tid + j * 256;          // 2048 = 64c * 32 f4
            int cc = chunk >> 5, m4 = chunk & 31;
            float4 d = *(const float4*)(x + ((size_t)n * C_ + cg * 64 + cc) * TV + m0 + m4 * 4);
            ushort* dst = &scratch[cc * 140 + m4 * 4];
            dst[0] = f2bf(d.x); dst[1] = f2bf(d.y); dst[2] = f2bf(d.z); dst[3] = f2bf(d.w);
        }
        __syncthreads();
        int cc = tid & 63, mbase = tid >> 6;
#pragma unroll
        for (int j = 0; j < 32; j++) {
            int mm = mbase + j * 4;
            As[mm * 200 + cg * 64 + cc] = scratch[cc * 140 + mm];
        }
    }

    int wave = tid >> 6, lane = tid & 63;
    int mb = (wave >> 1) * 64, ob = (wave & 1) * 32;
    int lrow = lane & 15, lk = lane >> 4;

    // ---- loop over 9 o-tiles ----
    for (int oi = 0; oi < 9; oi++) {
        int o0 = oi * 64;
        __syncthreads();               // scratch/Bs free, prev MFMA reads done
#pragma unroll
        for (int j = 0; j < 12; j++) {
            int chunk = tid + j * 256;          // 3072 = 64 rows * 48 f4
            int r = chunk / 48, c4 = chunk % 48;
            float4 d = *(const float4*)(W + (size_t)(o0 + r) * C_ + c4 * 4);
            ushort* dst = &Bs[r * 200 + c4 * 4];
            dst[0] = f2bf(d.x); dst[1] = f2bf(d.y); dst[2] = f2bf(d.z); dst[3] = f2bf(d.w);
        }
        if (tid < 64) biasS[tid] = bias[o0 + tid];
        __syncthreads();

        f32x4 acc[4][2];
#pragma unroll
        for (int i = 0; i < 4; i++)
#pragma unroll
            for (int j = 0; j < 2; j++) acc[i][j] = (f32x4){0.f, 0.f, 0.f, 0.f};

#pragma unroll
        for (int ks = 0; ks < 6; ks++) {
            bf16x8 a[4], b[2];
#pragma unroll
            for (int mt = 0; mt < 4; mt++)
                a[mt] = *(const bf16x8*)&As[(mb + mt * 16 + lrow) * 200 + ks * 32 + lk * 8];
#pragma unroll
            for (int ot = 0; ot < 2; ot++)
                b[ot] = *(const bf16x8*)&Bs[(ob + ot * 16 + lrow) * 200 + ks * 32 + lk * 8];
#pragma unroll
            for (int mt = 0; mt < 4; mt++)
#pragma unroll
                for (int ot = 0; ot < 2; ot++)
                    acc[mt][ot] = MFMA16(a[mt], b[ot], acc[mt][ot]);
        }

        ushort* op = qkvT + ((size_t)n * TV + m0) * C3 + o0;
#pragma unroll
        for (int mt = 0; mt < 4; mt++) {
#pragma unroll
            for (int ot = 0; ot < 2; ot++) {
                int o = ob + ot * 16 + lrow;
                float bv = biasS[o];
#pragma unroll
                for (int r = 0; r < 4; r++) {
                    int m = mb + mt * 16 + lk * 4 + r;
                    op[(size_t)m * C3 + o] = f2bf(acc[mt][ot][r] + bv);
                }
            }
        }
    }
}

// ---------------------------------------------------------------------------
// K2p: partial[((n*3+s)*16+tc)] [u][v] = sum over 8 t's of q.k  (fp32)
// grid (16,3,64) = 3072 blocks; each wave handles 2 t's independently.
// ---------------------------------------------------------------------------
__global__ __launch_bounds__(256) void k2_att(const ushort* __restrict__ qkvT,
                                              float* __restrict__ partial) {
    int tc = blockIdx.x, s = blockIdx.y, n = blockIdx.z;
    __shared__ ushort tiles[4 * 2 * 32 * 72];   // [wave][q/k][32 rows][64+8]
    __shared__ float red[4 * 32 * 33];
    int tid = threadIdx.x, wave = tid >> 6, lane = tid & 63;
    ushort* myQ = &tiles[wave * 2 * 2304];
    ushort* myK = myQ + 2304;

    // zero pad rows 25..31 of both tiles (never written again)
    if (lane < 63) {
        *(uint4*)&myQ[1800 + lane * 8] = (uint4){0, 0, 0, 0};
        *(uint4*)&myK[1800 + lane * 8] = (uint4){0, 0, 0, 0};
    }

    const size_t nbase = (size_t)n * TV * C3;
    int qoff = s * MID;
    int koff = C_ + s * MID;
    int lrow = lane & 15, lk = lane >> 4;

    f32x4 acc[2][2];
#pragma unroll
    for (int i = 0; i < 2; i++)
#pragma unroll
        for (int j = 0; j < 2; j++) acc[i][j] = (f32x4){0.f, 0.f, 0.f, 0.f};

#pragma unroll
    for (int i = 0; i < 2; i++) {
        int t = tc * 8 + wave + 4 * i;
#pragma unroll
        for (int j = 0; j < 7; j++) {
            int idx = lane + j * 64;
            if (idx < 400) {
                int op = idx / 200, rr = idx % 200;
                int row = rr >> 3, c16 = rr & 7;
                int chan = (op ? koff : qoff) + c16 * 8;
                uint4 d = *(const uint4*)(qkvT + nbase + (size_t)(t * V_ + row) * C3 + chan);
                *(uint4*)((op ? myK : myQ) + row * 72 + c16 * 8) = d;
            }
        }
#pragma unroll
        for (int ks = 0; ks < 2; ks++) {
            bf16x8 a0 = *(const bf16x8*)&myQ[lrow * 72 + ks * 32 + lk * 8];
            bf16x8 a1 = *(const bf16x8*)&myQ[(16 + lrow) * 72 + ks * 32 + lk * 8];
            bf16x8 b0 = *(const bf16x8*)&myK[lrow * 72 + ks * 32 + lk * 8];
            bf16x8 b1 = *(const bf16x8*)&myK[(16 + lrow) * 72 + ks * 32 + lk * 8];
            acc[0][0] = MFMA16(a0, b0, acc[0][0]);
            acc[0][1] = MFMA16(a0, b1, acc[0][1]);
            acc[1][0] = MFMA16(a1, b0, acc[1][0]);
            acc[1][1] = MFMA16(a1, b1, acc[1][1]);
        }
    }

#pragma unroll
    for (int ub = 0; ub < 2; ub++)
#pragma unroll
        for (int vb = 0; vb < 2; vb++)
#pragma unroll
            for (int r = 0; r < 4; r++) {
                int u = ub * 16 + lk * 4 + r, v = vb * 16 + lrow;
                red[wave * 1056 + u * 33 + v] = acc[ub][vb][r];
            }
    __syncthreads();

    float* pb = partial + (((size_t)n * S_ + s) * NCHUNK + tc) * PSTRIDE;
    for (int idx = tid; idx < 1024; idx += 256) {
        int u = idx >> 5, v = idx & 31;
        if (u < V_ && v < V_) {
            float sum = red[u * 33 + v] + red[1056 + u * 33 + v] +
                        red[2112 + u * 33 + v] + red[3168 + u * 33 + v];
            pb[u * V_ + v] = sum;
        }
    }
}

// ---------------------------------------------------------------------------
// K2r: attOut[ns][r] = tanh(sum_j partial[ns][j][r] / 8192)
// ---------------------------------------------------------------------------
__global__ __launch_bounds__(256) void k2_reduce(const float* __restrict__ partial,
                                                 float* __restrict__ attOut) {
    int idx = blockIdx.x * 256 + threadIdx.x;
    if (idx >= 192 * 625) return;
    int ns = idx / 625, r = idx % 625;
    const float* p = partial + (size_t)ns * NCHUNK * PSTRIDE + r;
    float s = 0.f;
#pragma unroll
    for (int j = 0; j < NCHUNK; j++) s += p[j * PSTRIDE];
    attOut[(size_t)ns * 625 + r] = tanhf(s * (1.0f / 8192.0f));
}

// ---------------------------------------------------------------------------
// K3: yT[n][t*25+u][c'] = sum_v att[n][s(c')][u][v] * qkv_v[n][t*25+v][c']
// ---------------------------------------------------------------------------
__global__ __launch_bounds__(192) void k3_y(const ushort* __restrict__ qkvT,
                                            const float* __restrict__ attF,
                                            ushort* __restrict__ yT) {
    int t = blockIdx.x, n = blockIdx.y;
    __shared__ float attS[3 * 700];   // [s][u][28 pad]
    int tid = threadIdx.x;
    const float* ab = attF + (size_t)n * (S_ * V_ * V_);
    for (int idx = tid; idx < S_ * V_ * V_; idx += 192) {
        int s = idx / 625, r = idx % 625;
        attS[s * 700 + (r / 25) * 28 + (r % 25)] = ab[idx];
    }
    __syncthreads();

    int c = tid;
    int s = c >> 6;
    const ushort* vb = qkvT + ((size_t)n * TV + (size_t)t * V_) * C3 + 2 * C_ + c;
    float vreg[25];
#pragma unroll
    for (int v = 0; v < 25; v++) vreg[v] = bf2f(vb[(size_t)v * C3]);

    ushort* yb = yT + ((size_t)n * TV + (size_t)t * V_) * C_ + c;
    const float* as = &attS[s * 700];
    for (int u = 0; u < 25; u++) {
        float a = 0.f;
#pragma unroll
        for (int v = 0; v < 25; v++) a += as[u * 28 + v] * vreg[v];
        yb[(size_t)u * C_] = f2bf(a);
    }
}

// ---------------------------------------------------------------------------
// K4: out[n][o][m] = LeakyReLU(x + (yT.Wff^T)*inv[o] + shift[o], 0.1)  fp32
// m-tile 64, A staged once, loop 3 o-tiles; LDS-transposed fp32 epilogue.
// ---------------------------------------------------------------------------
__global__ __launch_bounds__(256) void k4_out(const ushort* __restrict__ yT,
                                              const float* __restrict__ Wff,
                                              const float* __restrict__ bff,
                                              const float* __restrict__ gamma,
                                              const float* __restrict__ beta,
                                              const float* __restrict__ rmean,
                                              const float* __restrict__ rvar,
                                              const float* __restrict__ x,
                                              float* __restrict__ out) {
    int m0 = blockIdx.x * 64, n = blockIdx.y;
    __shared__ ushort As[64 * 200];
    __shared__ ushort Bs[64 * 200];
    __shared__ float zT[64 * 68];      // [o][m], fp32
    __shared__ float invS[64], shiftS[64];
    int tid = threadIdx.x;

    const ushort* ab = yT + ((size_t)n * TV + m0) * C_;
#pragma unroll
    for (int j = 0; j < 6; j++) {
        int chunk = tid + j * 256;          // 1536 = 64 rows * 24 chunks
        int r = chunk / 24, c16 = chunk % 24;
        *(uint4*)&As[r * 200 + c16 * 8] = *(const uint4*)(ab + (size_t)r * C_ + c16 * 8);
    }

    int wave = tid >> 6, lane = tid & 63;
    int mb = (wave >> 1) * 32, obw = (wave & 1) * 32;
    int lrow = lane & 15, lk = lane >> 4;

    for (int oi = 0; oi < 3; oi++) {
        int o0 = oi * 64;
        __syncthreads();               // As staged / prev epilogue+MFMA done
#pragma unroll
        for (int j = 0; j < 12; j++) {
            int chunk = tid + j * 256;          // 3072 = 64 rows * 48 f4
            int r = chunk / 48, c4 = chunk % 48;
            float4 d = *(const float4*)(Wff + (size_t)(o0 + r) * C_ + c4 * 4);
            ushort* dst = &Bs[r * 200 + c4 * 4];
            dst[0] = f2bf(d.x); dst[1] = f2bf(d.y); dst[2] = f2bf(d.z); dst[3] = f2bf(d.w);
        }
        if (tid < 64) {
            int o = o0 + tid;
            float inv = gamma[o] * rsqrtf(rvar[o] + 1e-5f);
            invS[tid] = inv;
            shiftS[tid] = beta[o] - rmean[o] * inv + bff[o] * inv;
        }
        __syncthreads();

        f32x4 acc[2][2];
#pragma unroll
        for (int i = 0; i < 2; i++)
#pragma unroll
            for (int j = 0; j < 2; j++) acc[i][j] = (f32x4){0.f, 0.f, 0.f, 0.f};

#pragma unroll
        for (int ks = 0; ks < 6; ks++) {
            bf16x8 a[2], b[2];
#pragma unroll
            for (int mt = 0; mt < 2; mt++)
                a[mt] = *(const bf16x8*)&As[(mb + mt * 16 + lrow) * 200 + ks * 32 + lk * 8];
#pragma unroll
            for (int ot = 0; ot < 2; ot++)
                b[ot] = *(const bf16x8*)&Bs[(obw + ot * 16 + lrow) * 200 + ks * 32 + lk * 8];
#pragma unroll
            for (int mt = 0; mt < 2; mt++)
#pragma unroll
                for (int ot = 0; ot < 2; ot++)
                    acc[mt][ot] = MFMA16(a[mt], b[ot], acc[mt][ot]);
        }

#pragma unroll
        for (int mt = 0; mt < 2; mt++)
#pragma unroll
            for (int ot = 0; ot < 2; ot++) {
                int o = obw + ot * 16 + lrow;
                float inv = invS[o], sh = shiftS[o];
#pragma unroll
                for (int r = 0; r < 4; r++) {
                    int m = mb + mt * 16 + lk * 4 + r;
                    zT[o * 68 + m] = acc[mt][ot][r] * inv + sh;
                }
            }
        __syncthreads();

        const float* xb = x + ((size_t)n * C_ + o0) * TV + m0;
        float* ob2 = out + ((size_t)n * C_ + o0) * TV + m0;
#pragma unroll
        for (int j = 0; j < 4; j++) {
            int chunk = tid + j * 256;          // 1024 = 64 rows * 16 f4
            int o = chunk >> 4, m4 = chunk & 15;
            float4 zv = *(float4*)&zT[o * 68 + m4 * 4];
            float4 xv = *(const float4*)(xb + (size_t)o * TV + m4 * 4);
            float4 res; float a;
            a = xv.x + zv.x; res.x = (a >= 0.f) ? a : 0.1f * a;
            a = xv.y + zv.y; res.y = (a >= 0.f) ? a : 0.1f * a;
            a = xv.z + zv.z; res.z = (a >= 0.f) ? a : 0.1f * a;
            a = xv.w + zv.w; res.w = (a >= 0.f) ? a : 0.1f * a;
            *(float4*)(ob2 + (size_t)o * TV + m4 * 4) = res;
        }
    }
}

// ---------------------------------------------------------------------------
extern "C" void kernel_launch(void* const* d_in, const int* in_sizes, int n_in,
                              void* d_out, int out_size, void* d_ws, size_t ws_size,
                              hipStream_t stream) {
    (void)in_sizes; (void)n_in; (void)out_size; (void)ws_size;
    const float* x    = (const float*)d_in[0];
    const float* Wqkv = (const float*)d_in[1];
    const float* bqkv = (const float*)d_in[2];
    const float* Wff  = (const float*)d_in[3];
    const float* bff  = (const float*)d_in[4];
    const float* gam  = (const float*)d_in[5];
    const float* bet  = (const float*)d_in[6];
    const float* rme  = (const float*)d_in[7];
    const float* rva  = (const float*)d_in[8];
    float* out = (float*)d_out;
    float* attOut = out + OUT_ELEMS;   // fp32 att segment of the output tuple

    char* ws = (char*)d_ws;
    ushort* qkvT = (ushort*)ws;                        // 235,929,600 B
    // partial (7.86 MB) and yT (78.6 MB) alias: partial is dead before k3 runs
    float*  partial = (float*)(ws + 235929600);
    ushort* yT      = (ushort*)(ws + 235929600);

    k1_qkv<<<dim3(25, 64), 256, 0, stream>>>(x, Wqkv, bqkv, qkvT);
    k2_att<<<dim3(NCHUNK, 3, 64), 256, 0, stream>>>(qkvT, partial);
    k2_reduce<<<dim3(469), 256, 0, stream>>>(partial, attOut);
    k3_y<<<dim3(128, 64), 192, 0, stream>>>(qkvT, attOut, yT);
    k4_out<<<dim3(50, 64), 256, 0, stream>>>(yT, Wff, bff, gam, bet, rme, rva, x, out);
}

// Round 4
// 515.647 us; speedup vs baseline: 1.2217x; 1.0215x over previous
//
#include <hip/hip_runtime.h>
#include <hip/hip_bf16.h>

typedef __attribute__((ext_vector_type(8))) short bf16x8;
typedef __attribute__((ext_vector_type(4))) float f32x4;

#define MFMA16(a, b, c) __builtin_amdgcn_mfma_f32_16x16x32_bf16((a), (b), (c), 0, 0, 0)

#define N_ 64
#define C_ 192
#define T_ 128
#define V_ 25
#define S_ 3
#define MID 64
#define TV 3200          // T_*V_
#define C3 576           // 3*C_
#define OUT_ELEMS 39321600ULL
#define NCHUNK 16        // T-chunks for k2 partials
#define PSTRIDE 640      // padded 25*25 partial stride (floats)

static __device__ __forceinline__ float bf2f(ushort u) {
    union { unsigned int i; float f; } x; x.i = ((unsigned int)u) << 16; return x.f;
}
static __device__ __forceinline__ ushort f2bf(float f) {
    union { float f; unsigned int i; } x; x.f = f;
    unsigned int r = x.i + 0x7fffu + ((x.i >> 16) & 1u);
    return (ushort)(r >> 16);
}
static __device__ __forceinline__ unsigned int pack2(float a, float b) {
    return (unsigned int)f2bf(a) | ((unsigned int)f2bf(b) << 16);
}

// ---------------------------------------------------------------------------
// K1: qkvT[n][m][o] = sum_k x[n][k][m] * Wqkv[o][k] + bqkv[o]   (bf16 out)
// m-tile 64, grid (50,64)=3200 blocks, LDS ~51.5KB -> 3 blocks/CU.
// Fused fp32->bf16 transpose staging via odd-dword-stride scratch (no bank
// conflicts). A staged once; loop 9 o-tiles (W is L2-resident).
// ---------------------------------------------------------------------------
__global__ __launch_bounds__(256) void k1_qkv(const float* __restrict__ x,
                                              const float* __restrict__ W,
                                              const float* __restrict__ bias,
                                              ushort* __restrict__ qkvT) {
    int m0 = blockIdx.x * 64, n = blockIdx.y;
    __shared__ ushort As[64 * 200];    // [m][c], c stride 200 shorts
    __shared__ ushort Bs[64 * 200];    // [o][c]; front 13.4KB aliased as scratch
    __shared__ float biasS[64];
    unsigned int* scratchU = (unsigned int*)Bs;   // 96 rows x 35 dwords (odd stride)
    ushort* scratchS = Bs;                        // same, short view: row stride 70
    int tid = threadIdx.x;

    // ---- stage A: 2 groups of 96 channels ----
    for (int cg = 0; cg < 2; cg++) {
        if (cg) __syncthreads();       // transpose reads of scratch done
#pragma unroll
        for (int j = 0; j < 6; j++) {
            int chunk = tid + j * 256;          // 1536 = 96c * 16 f4
            int cc = chunk >> 4, m4 = chunk & 15;
            float4 d = *(const float4*)(x + ((size_t)n * C_ + cg * 96 + cc) * TV + m0 + m4 * 4);
            scratchU[cc * 35 + m4 * 2]     = pack2(d.x, d.y);
            scratchU[cc * 35 + m4 * 2 + 1] = pack2(d.z, d.w);
        }
        __syncthreads();
#pragma unroll
        for (int j = 0; j < 24; j++) {
            int idx = tid + j * 256;            // 6144 = 64m * 96c
            int mm = idx / 96, cc = idx % 96;
            As[mm * 200 + cg * 96 + cc] = scratchS[cc * 70 + mm];
        }
    }

    int wave = tid >> 6, lane = tid & 63;
    int mb = (wave >> 1) * 32, ob = (wave & 1) * 32;
    int lrow = lane & 15, lk = lane >> 4;

    // ---- loop over 9 o-tiles ----
    for (int oi = 0; oi < 9; oi++) {
        int o0 = oi * 64;
        __syncthreads();               // scratch reads / prev MFMA Bs reads done
#pragma unroll
        for (int j = 0; j < 12; j++) {
            int chunk = tid + j * 256;          // 3072 = 64 rows * 48 f4
            int r = chunk / 48, c4 = chunk % 48;
            float4 d = *(const float4*)(W + (size_t)(o0 + r) * C_ + c4 * 4);
            ushort* dst = &Bs[r * 200 + c4 * 4];
            dst[0] = f2bf(d.x); dst[1] = f2bf(d.y); dst[2] = f2bf(d.z); dst[3] = f2bf(d.w);
        }
        if (tid < 64) biasS[tid] = bias[o0 + tid];
        __syncthreads();

        f32x4 acc[2][2];
#pragma unroll
        for (int i = 0; i < 2; i++)
#pragma unroll
            for (int j = 0; j < 2; j++) acc[i][j] = (f32x4){0.f, 0.f, 0.f, 0.f};

#pragma unroll
        for (int ks = 0; ks < 6; ks++) {
            bf16x8 a[2], b[2];
#pragma unroll
            for (int mt = 0; mt < 2; mt++)
                a[mt] = *(const bf16x8*)&As[(mb + mt * 16 + lrow) * 200 + ks * 32 + lk * 8];
#pragma unroll
            for (int ot = 0; ot < 2; ot++)
                b[ot] = *(const bf16x8*)&Bs[(ob + ot * 16 + lrow) * 200 + ks * 32 + lk * 8];
#pragma unroll
            for (int mt = 0; mt < 2; mt++)
#pragma unroll
                for (int ot = 0; ot < 2; ot++)
                    acc[mt][ot] = MFMA16(a[mt], b[ot], acc[mt][ot]);
        }

        ushort* op = qkvT + ((size_t)n * TV + m0) * C3 + o0;
#pragma unroll
        for (int mt = 0; mt < 2; mt++) {
#pragma unroll
            for (int ot = 0; ot < 2; ot++) {
                int o = ob + ot * 16 + lrow;
                float bv = biasS[o];
#pragma unroll
                for (int r = 0; r < 4; r++) {
                    int m = mb + mt * 16 + lk * 4 + r;
                    op[(size_t)m * C3 + o] = f2bf(acc[mt][ot][r] + bv);
                }
            }
        }
    }
}

// ---------------------------------------------------------------------------
// K2p: partial[((n*3+s)*16+tc)][u][v] = sum over 8 t's of q.k  (fp32)
// grid (16,3,64) = 3072 blocks; each wave handles 2 t's independently.
// ---------------------------------------------------------------------------
__global__ __launch_bounds__(256) void k2_att(const ushort* __restrict__ qkvT,
                                              float* __restrict__ partial) {
    int tc = blockIdx.x, s = blockIdx.y, n = blockIdx.z;
    __shared__ ushort tiles[4 * 2 * 32 * 72];   // [wave][q/k][32 rows][64+8]
    __shared__ float red[4 * 32 * 33];
    int tid = threadIdx.x, wave = tid >> 6, lane = tid & 63;
    ushort* myQ = &tiles[wave * 2 * 2304];
    ushort* myK = myQ + 2304;

    // zero pad rows 25..31 of both tiles (never written again)
    if (lane < 63) {
        *(uint4*)&myQ[1800 + lane * 8] = (uint4){0, 0, 0, 0};
        *(uint4*)&myK[1800 + lane * 8] = (uint4){0, 0, 0, 0};
    }

    const size_t nbase = (size_t)n * TV * C3;
    int qoff = s * MID;
    int koff = C_ + s * MID;
    int lrow = lane & 15, lk = lane >> 4;

    f32x4 acc[2][2];
#pragma unroll
    for (int i = 0; i < 2; i++)
#pragma unroll
        for (int j = 0; j < 2; j++) acc[i][j] = (f32x4){0.f, 0.f, 0.f, 0.f};

#pragma unroll
    for (int i = 0; i < 2; i++) {
        int t = tc * 8 + wave + 4 * i;
#pragma unroll
        for (int j = 0; j < 7; j++) {
            int idx = lane + j * 64;
            if (idx < 400) {
                int op = idx / 200, rr = idx % 200;
                int row = rr >> 3, c16 = rr & 7;
                int chan = (op ? koff : qoff) + c16 * 8;
                uint4 d = *(const uint4*)(qkvT + nbase + (size_t)(t * V_ + row) * C3 + chan);
                *(uint4*)((op ? myK : myQ) + row * 72 + c16 * 8) = d;
            }
        }
#pragma unroll
        for (int ks = 0; ks < 2; ks++) {
            bf16x8 a0 = *(const bf16x8*)&myQ[lrow * 72 + ks * 32 + lk * 8];
            bf16x8 a1 = *(const bf16x8*)&myQ[(16 + lrow) * 72 + ks * 32 + lk * 8];
            bf16x8 b0 = *(const bf16x8*)&myK[lrow * 72 + ks * 32 + lk * 8];
            bf16x8 b1 = *(const bf16x8*)&myK[(16 + lrow) * 72 + ks * 32 + lk * 8];
            acc[0][0] = MFMA16(a0, b0, acc[0][0]);
            acc[0][1] = MFMA16(a0, b1, acc[0][1]);
            acc[1][0] = MFMA16(a1, b0, acc[1][0]);
            acc[1][1] = MFMA16(a1, b1, acc[1][1]);
        }
    }

#pragma unroll
    for (int ub = 0; ub < 2; ub++)
#pragma unroll
        for (int vb = 0; vb < 2; vb++)
#pragma unroll
            for (int r = 0; r < 4; r++) {
                int u = ub * 16 + lk * 4 + r, v = vb * 16 + lrow;
                red[wave * 1056 + u * 33 + v] = acc[ub][vb][r];
            }
    __syncthreads();

    float* pb = partial + (((size_t)n * S_ + s) * NCHUNK + tc) * PSTRIDE;
    for (int idx = tid; idx < 1024; idx += 256) {
        int u = idx >> 5, v = idx & 31;
        if (u < V_ && v < V_) {
            float sum = red[u * 33 + v] + red[1056 + u * 33 + v] +
                        red[2112 + u * 33 + v] + red[3168 + u * 33 + v];
            pb[u * V_ + v] = sum;
        }
    }
}

// ---------------------------------------------------------------------------
// K2r: attOut[ns][r] = tanh(sum_j partial[ns][j][r] / 8192)
// ---------------------------------------------------------------------------
__global__ __launch_bounds__(256) void k2_reduce(const float* __restrict__ partial,
                                                 float* __restrict__ attOut) {
    int idx = blockIdx.x * 256 + threadIdx.x;
    if (idx >= 192 * 625) return;
    int ns = idx / 625, r = idx % 625;
    const float* p = partial + (size_t)ns * NCHUNK * PSTRIDE + r;
    float s = 0.f;
#pragma unroll
    for (int j = 0; j < NCHUNK; j++) s += p[j * PSTRIDE];
    attOut[(size_t)ns * 625 + r] = tanhf(s * (1.0f / 8192.0f));
}

// ---------------------------------------------------------------------------
// K3: yT[n][t*25+u][c'] = sum_v att[n][s(c')][u][v] * qkv_v[n][t*25+v][c']
// ---------------------------------------------------------------------------
__global__ __launch_bounds__(192) void k3_y(const ushort* __restrict__ qkvT,
                                            const float* __restrict__ attF,
                                            ushort* __restrict__ yT) {
    int t = blockIdx.x, n = blockIdx.y;
    __shared__ float attS[3 * 700];   // [s][u][28 pad]
    int tid = threadIdx.x;
    const float* ab = attF + (size_t)n * (S_ * V_ * V_);
    for (int idx = tid; idx < S_ * V_ * V_; idx += 192) {
        int s = idx / 625, r = idx % 625;
        attS[s * 700 + (r / 25) * 28 + (r % 25)] = ab[idx];
    }
    __syncthreads();

    int c = tid;
    int s = c >> 6;
    const ushort* vb = qkvT + ((size_t)n * TV + (size_t)t * V_) * C3 + 2 * C_ + c;
    float vreg[25];
#pragma unroll
    for (int v = 0; v < 25; v++) vreg[v] = bf2f(vb[(size_t)v * C3]);

    ushort* yb = yT + ((size_t)n * TV + (size_t)t * V_) * C_ + c;
    const float* as = &attS[s * 700];
    for (int u = 0; u < 25; u++) {
        float a = 0.f;
#pragma unroll
        for (int v = 0; v < 25; v++) a += as[u * 28 + v] * vreg[v];
        yb[(size_t)u * C_] = f2bf(a);
    }
}

// ---------------------------------------------------------------------------
// K4: out[n][o][m] = LeakyReLU(x + (yT.Wff^T)*inv[o] + shift[o], 0.1)  fp32
// m-tile 64, A staged once, 3 o-tiles; zT aliases Bs -> LDS ~51.5KB,
// 3 blocks/CU. LDS-transposed fp32 epilogue with float4 stores.
// ---------------------------------------------------------------------------
__global__ __launch_bounds__(256) void k4_out(const ushort* __restrict__ yT,
                                              const float* __restrict__ Wff,
                                              const float* __restrict__ bff,
                                              const float* __restrict__ gamma,
                                              const float* __restrict__ beta,
                                              const float* __restrict__ rmean,
                                              const float* __restrict__ rvar,
                                              const float* __restrict__ x,
                                              float* __restrict__ out) {
    int m0 = blockIdx.x * 64, n = blockIdx.y;
    __shared__ ushort As[64 * 200];
    __shared__ ushort Bs[64 * 200];    // 25.6KB; reused as fp32 zT[64][68] (17.4KB)
    __shared__ float invS[64], shiftS[64];
    float* zT = (float*)Bs;
    int tid = threadIdx.x;

    const ushort* ab = yT + ((size_t)n * TV + m0) * C_;
#pragma unroll
    for (int j = 0; j < 6; j++) {
        int chunk = tid + j * 256;          // 1536 = 64 rows * 24 chunks
        int r = chunk / 24, c16 = chunk % 24;
        *(uint4*)&As[r * 200 + c16 * 8] = *(const uint4*)(ab + (size_t)r * C_ + c16 * 8);
    }

    int wave = tid >> 6, lane = tid & 63;
    int mb = (wave >> 1) * 32, obw = (wave & 1) * 32;
    int lrow = lane & 15, lk = lane >> 4;

    for (int oi = 0; oi < 3; oi++) {
        int o0 = oi * 64;
        __syncthreads();               // As staged / prev epilogue zT reads done
#pragma unroll
        for (int j = 0; j < 12; j++) {
            int chunk = tid + j * 256;          // 3072 = 64 rows * 48 f4
            int r = chunk / 48, c4 = chunk % 48;
            float4 d = *(const float4*)(Wff + (size_t)(o0 + r) * C_ + c4 * 4);
            ushort* dst = &Bs[r * 200 + c4 * 4];
            dst[0] = f2bf(d.x); dst[1] = f2bf(d.y); dst[2] = f2bf(d.z); dst[3] = f2bf(d.w);
        }
        if (tid < 64) {
            int o = o0 + tid;
            float inv = gamma[o] * rsqrtf(rvar[o] + 1e-5f);
            invS[tid] = inv;
            shiftS[tid] = beta[o] - rmean[o] * inv + bff[o] * inv;
        }
        __syncthreads();

        f32x4 acc[2][2];
#pragma unroll
        for (int i = 0; i < 2; i++)
#pragma unroll
            for (int j = 0; j < 2; j++) acc[i][j] = (f32x4){0.f, 0.f, 0.f, 0.f};

#pragma unroll
        for (int ks = 0; ks < 6; ks++) {
            bf16x8 a[2], b[2];
#pragma unroll
            for (int mt = 0; mt < 2; mt++)
                a[mt] = *(const bf16x8*)&As[(mb + mt * 16 + lrow) * 200 + ks * 32 + lk * 8];
#pragma unroll
            for (int ot = 0; ot < 2; ot++)
                b[ot] = *(const bf16x8*)&Bs[(obw + ot * 16 + lrow) * 200 + ks * 32 + lk * 8];
#pragma unroll
            for (int mt = 0; mt < 2; mt++)
#pragma unroll
                for (int ot = 0; ot < 2; ot++)
                    acc[mt][ot] = MFMA16(a[mt], b[ot], acc[mt][ot]);
        }

        __syncthreads();               // all waves done reading Bs (W)
#pragma unroll
        for (int mt = 0; mt < 2; mt++)
#pragma unroll
            for (int ot = 0; ot < 2; ot++) {
                int o = obw + ot * 16 + lrow;
                float inv = invS[o], sh = shiftS[o];
#pragma unroll
                for (int r = 0; r < 4; r++) {
                    int m = mb + mt * 16 + lk * 4 + r;
                    zT[o * 68 + m] = acc[mt][ot][r] * inv + sh;
                }
            }
        __syncthreads();

        const float* xb = x + ((size_t)n * C_ + o0) * TV + m0;
        float* ob2 = out + ((size_t)n * C_ + o0) * TV + m0;
#pragma unroll
        for (int j = 0; j < 4; j++) {
            int chunk = tid + j * 256;          // 1024 = 64 rows * 16 f4
            int o = chunk >> 4, m4 = chunk & 15;
            float4 zv = *(float4*)&zT[o * 68 + m4 * 4];
            float4 xv = *(const float4*)(xb + (size_t)o * TV + m4 * 4);
            float4 res; float a;
            a = xv.x + zv.x; res.x = (a >= 0.f) ? a : 0.1f * a;
            a = xv.y + zv.y; res.y = (a >= 0.f) ? a : 0.1f * a;
            a = xv.z + zv.z; res.z = (a >= 0.f) ? a : 0.1f * a;
            a = xv.w + zv.w; res.w = (a >= 0.f) ? a : 0.1f * a;
            *(float4*)(ob2 + (size_t)o * TV + m4 * 4) = res;
        }
    }
}

// ---------------------------------------------------------------------------
extern "C" void kernel_launch(void* const* d_in, const int* in_sizes, int n_in,
                              void* d_out, int out_size, void* d_ws, size_t ws_size,
                              hipStream_t stream) {
    (void)in_sizes; (void)n_in; (void)out_size; (void)ws_size;
    const float* x    = (const float*)d_in[0];
    const float* Wqkv = (const float*)d_in[1];
    const float* bqkv = (const float*)d_in[2];
    const float* Wff  = (const float*)d_in[3];
    const float* bff  = (const float*)d_in[4];
    const float* gam  = (const float*)d_in[5];
    const float* bet  = (const float*)d_in[6];
    const float* rme  = (const float*)d_in[7];
    const float* rva  = (const float*)d_in[8];
    float* out = (float*)d_out;
    float* attOut = out + OUT_ELEMS;   // fp32 att segment of the output tuple

    char* ws = (char*)d_ws;
    ushort* qkvT = (ushort*)ws;                        // 235,929,600 B
    // partial (7.86 MB) and yT (78.6 MB) alias: partial is dead before k3 runs
    float*  partial = (float*)(ws + 235929600);
    ushort* yT      = (ushort*)(ws + 235929600);

    k1_qkv<<<dim3(50, 64), 256, 0, stream>>>(x, Wqkv, bqkv, qkvT);
    k2_att<<<dim3(NCHUNK, 3, 64), 256, 0, stream>>>(qkvT, partial);
    k2_reduce<<<dim3(469), 256, 0, stream>>>(partial, attOut);
    k3_y<<<dim3(128, 64), 192, 0, stream>>>(qkvT, attOut, yT);
    k4_out<<<dim3(50, 64), 256, 0, stream>>>(yT, Wff, bff, gam, bet, rme, rva, x, out);
}